// Round 1
// 258.827 us; speedup vs baseline: 1.0296x; 1.0296x over previous
//
#include <hip/hip_runtime.h>
#include <hip/hip_bf16.h>

// Problem constants (setup_inputs: B=8, N=2048, D=768, fp32)
static constexpr int BB = 8;
static constexpr int NN = 2048;
static constexpr int DD = 768;

typedef __attribute__((ext_vector_type(8))) __bf16 bf16x8;
typedef __attribute__((ext_vector_type(4))) float f32x4;

__device__ __forceinline__ void gload_lds16(const __hip_bfloat16* g, __hip_bfloat16* l) {
  __builtin_amdgcn_global_load_lds(
      (const __attribute__((address_space(1))) void*)g,
      (__attribute__((address_space(3))) void*)l,
      16, 0, 0);
}

// ---------------- prep: normalize mid -> Qn bf16 (+zero lsum/conf) ----------------
static constexpr int NORM_BLOCKS = (BB * NN) / 4;                 // 4096
static constexpr int TRANS_BLOCKS = (DD / 32) * (NN / 32) * BB;   // 24*64*8 = 12288
static constexpr int QK_BLOCKS = BB * 136;                        // 1088

__global__ void prep_kernel(const float* __restrict__ mid, __hip_bfloat16* __restrict__ Qn,
                            float* __restrict__ lsum, float* __restrict__ conf) {
  const int t = threadIdx.x;
  const int wave = t >> 6;
  const int lane = t & 63;
  const size_t row = (size_t)blockIdx.x * 4 + wave;
  if (lane == 0) { lsum[row] = 0.f; conf[row] = 0.f; }
  const float* src = mid + row * DD;

  float4 v[3];
  float ss = 0.f;
#pragma unroll
  for (int j = 0; j < 3; ++j) {
    v[j] = *(const float4*)(src + j * 256 + lane * 4);
    ss += v[j].x * v[j].x + v[j].y * v[j].y + v[j].z * v[j].z + v[j].w * v[j].w;
  }
#pragma unroll
  for (int o = 32; o; o >>= 1) ss += __shfl_xor(ss, o, 64);
  const float inv = 1.0f / fmaxf(sqrtf(ss), 1e-12f);

  __hip_bfloat16* dst = Qn + row * DD;
#pragma unroll
  for (int j = 0; j < 3; ++j) {
    union { ushort4 u; __hip_bfloat16 h[4]; } pk;
    pk.h[0] = __float2bfloat16(v[j].x * inv);
    pk.h[1] = __float2bfloat16(v[j].y * inv);
    pk.h[2] = __float2bfloat16(v[j].z * inv);
    pk.h[3] = __float2bfloat16(v[j].w * inv);
    *(ushort4*)(dst + j * 256 + lane * 4) = pk.u;
  }
}

// ---------------- GEMM1 (symmetric): S = Qn·Qnᵀ, upper-triangle tiles only ----------------
// Off-diag tiles scheduled first, diagonal tiles (lighter epilogue) last; transpose blocks
// (F -> Vt, only consumed by the pv kernel) appended after to backfill the tail round.
__global__ __launch_bounds__(256) void gemm_qk_kernel(
    const __hip_bfloat16* __restrict__ Qn,
    __hip_bfloat16* __restrict__ P,
    float* __restrict__ lsum,
    unsigned* __restrict__ conf,
    const float* __restrict__ F,
    __hip_bfloat16* __restrict__ Vt) {
  __shared__ __hip_bfloat16 smem[4 * 128 * 64];  // 64 KB: dbuf staging; epilogue: Pt(32K)+Mt(32K)
  const int t = threadIdx.x;

  if (blockIdx.x >= QK_BLOCKS) {
    // ---- transpose path: F[b][n][d] fp32 -> Vt[b][d][n] bf16 ----
    __hip_bfloat16 (*tile)[33] = reinterpret_cast<__hip_bfloat16(*)[33]>(smem);
    const int bid = blockIdx.x - QK_BLOCKS;
    const int bx = bid % 24;
    const int rest = bid / 24;
    const int by = rest & 63;
    const int b = rest >> 6;
    const int n0 = by * 32;
    const int d0 = bx * 32;
    const int tx = t & 31, ty = t >> 5;
#pragma unroll
    for (int i = 0; i < 4; ++i) {
      const int n = n0 + ty + i * 8;
      tile[ty + i * 8][tx] = __float2bfloat16(F[((size_t)b * NN + n) * DD + d0 + tx]);
    }
    __syncthreads();
#pragma unroll
    for (int i = 0; i < 4; ++i) {
      const int d = d0 + ty + i * 8;
      Vt[((size_t)b * DD + d) * NN + n0 + tx] = tile[tx][ty + i * 8];
    }
    return;
  }

  const int d = blockIdx.x;                // 0..1087 (8 batches x 136 triangle tiles)
  const int b = d & 7;                     // XCD k <- batch k (Qn batch 3 MB fits XCD L2)
  int rem = d >> 3;                        // 0..135
  int ti, tj;
  if (rem < 120) {                         // strict upper triangle (i<j), 120 pairs
    ti = 0;
    while (rem >= 15 - ti) { rem -= 15 - ti; ++ti; }
    tj = ti + 1 + rem;
  } else {                                 // 16 diagonal tiles, scheduled last
    ti = tj = rem - 120;
  }
  const int rowBase = ti * 128;
  const int colBase = tj * 128;
  const bool offdiag = (ti != tj);

  const int lane = t & 63;
  const int wave = t >> 6;
  const int wRow = wave >> 1;
  const int wCol = wave & 1;
  const int quad = lane >> 4;
  const int l16 = lane & 15;

  const __hip_bfloat16* Abase = Qn + ((size_t)b * NN + rowBase) * DD;
  const __hip_bfloat16* Bbase = Qn + ((size_t)b * NN + colBase) * DD;

  // staging slots (lane-contiguous dest for global_load_lds; source XOR-swizzled)
  int srow[4], scol[4], sc8[4];
#pragma unroll
  for (int i = 0; i < 4; ++i) {
    const int c = i * 256 + t;
    srow[i] = c >> 3;
    const int col8 = (c & 7) ^ ((c >> 3) & 7);
    scol[i] = col8 * 8;
    sc8[i] = c * 8;
  }

  f32x4 acc[4][4];
#pragma unroll
  for (int i = 0; i < 4; ++i)
#pragma unroll
    for (int j = 0; j < 4; ++j) acc[i][j] = (f32x4){0.f, 0.f, 0.f, 0.f};

  // prologue: stage tile 0 into buf 0
  {
    __hip_bfloat16* As = smem;
    __hip_bfloat16* Bs = smem + 128 * 64;
#pragma unroll
    for (int i = 0; i < 4; ++i) {
      gload_lds16(Abase + (size_t)srow[i] * DD + scol[i], As + sc8[i]);
      gload_lds16(Bbase + (size_t)srow[i] * DD + scol[i], Bs + sc8[i]);
    }
  }

  constexpr int NK = DD / 64;  // 12
  for (int kk = 0; kk < NK; ++kk) {
    const int cur = kk & 1;
    __syncthreads();  // buf[cur] staged; buf[1-cur] consumed
    if (kk + 1 < NK) {
      __hip_bfloat16* As = smem + (1 - cur) * 2 * 128 * 64;
      __hip_bfloat16* Bs = As + 128 * 64;
      const int k0 = (kk + 1) * 64;
#pragma unroll
      for (int i = 0; i < 4; ++i) {
        gload_lds16(Abase + (size_t)srow[i] * DD + (k0 + scol[i]), As + sc8[i]);
        gload_lds16(Bbase + (size_t)srow[i] * DD + (k0 + scol[i]), Bs + sc8[i]);
      }
    }
    const __hip_bfloat16* As = smem + cur * 2 * 128 * 64;
    const __hip_bfloat16* Bs = As + 128 * 64;
#pragma unroll
    for (int ks = 0; ks < 2; ++ks) {
      bf16x8 af[4], bfr[4];
#pragma unroll
      for (int i = 0; i < 4; ++i) {
        const int rA = wRow * 64 + i * 16 + l16;
        const int rB = wCol * 64 + i * 16 + l16;
        const int pA = (ks * 4 + quad) ^ (rA & 7);
        const int pB = (ks * 4 + quad) ^ (rB & 7);
        af[i]  = *(const bf16x8*)(As + rA * 64 + pA * 8);
        bfr[i] = *(const bf16x8*)(Bs + rB * 64 + pB * 8);
      }
#pragma unroll
      for (int mi = 0; mi < 4; ++mi)
#pragma unroll
        for (int ni = 0; ni < 4; ++ni)
          acc[mi][ni] = __builtin_amdgcn_mfma_f32_16x16x32_bf16(af[mi], bfr[ni], acc[mi][ni], 0, 0, 0);
    }
  }

  __syncthreads();  // K-loop LDS reads done; reuse smem as Pt + Mt (XOR-swizzled)
  __hip_bfloat16* Pt = smem;              // direct tile  [128][128]
  __hip_bfloat16* Mt = smem + 128 * 128;  // mirror tile  [128][128]

  float csum[4] = {0.f, 0.f, 0.f, 0.f};
  float cmax[4] = {0.f, 0.f, 0.f, 0.f};  // clamp at 0 valid (diag of full matrix is 0)

#pragma unroll
  for (int mi = 0; mi < 4; ++mi) {
    const int rbase = wRow * 64 + mi * 16 + quad * 4;
    float rs[4] = {0.f, 0.f, 0.f, 0.f};
    float rm[4] = {0.f, 0.f, 0.f, 0.f};
#pragma unroll
    for (int ni = 0; ni < 4; ++ni) {
      const int colL = wCol * 64 + ni * 16 + l16;
      const int col_g = colBase + colL;
      union { ushort4 u; __hip_bfloat16 h[4]; } pk;
#pragma unroll
      for (int r = 0; r < 4; ++r) {
        const int rowL = rbase + r;
        float s = acc[mi][ni][r];
        if (rowBase + rowL == col_g) s = 0.f;   // only possible on diagonal tiles
        const float p = __expf(s);              // T=1; |s|<=1 so no max-subtraction needed
        rm[r] = fmaxf(rm[r], s);
        rs[r] += p;
        csum[ni] += p;
        cmax[ni] = fmaxf(cmax[ni], s);
        pk.h[r] = __float2bfloat16(p);
        Pt[rowL * 128 + (((colL >> 3) ^ (rowL & 7)) << 3) + (colL & 7)] = pk.h[r];
      }
      if (offdiag) {  // mirror: Mt[colL][rbase..rbase+3] (8B-aligned: rbase%4==0, rbase&7 in {0,4})
        *(ushort4*)(Mt + colL * 128 + (((rbase >> 3) ^ (colL & 7)) << 3) + (rbase & 7)) = pk.u;
      }
    }
#pragma unroll
    for (int r = 0; r < 4; ++r) {
      float ps = rs[r], mx = rm[r];
#pragma unroll
      for (int o = 1; o < 16; o <<= 1) {
        ps += __shfl_xor(ps, o, 64);
        mx = fmaxf(mx, __shfl_xor(mx, o, 64));
      }
      if (l16 == 0) {
        const int row_g = rowBase + rbase + r;
        atomicAdd(lsum + (size_t)b * NN + row_g, ps);
        atomicMax(conf + (size_t)b * NN + row_g, __float_as_uint(mx));  // nonneg: uint order == float order
      }
    }
  }

  // column stats -> stripe tj rows (mirror contribution), off-diag only
  if (offdiag) {
#pragma unroll
    for (int ni = 0; ni < 4; ++ni) {
      float cs = csum[ni];
      float cm = cmax[ni];
      cs += __shfl_xor(cs, 16, 64); cm = fmaxf(cm, __shfl_xor(cm, 16, 64));
      cs += __shfl_xor(cs, 32, 64); cm = fmaxf(cm, __shfl_xor(cm, 32, 64));
      if (quad == 0) {
        const int col_g = colBase + wCol * 64 + ni * 16 + l16;
        atomicAdd(lsum + (size_t)b * NN + col_g, cs);
        atomicMax(conf + (size_t)b * NN + col_g, __float_as_uint(cm));
      }
    }
  }

  __syncthreads();
  // direct store: P[b][stripe ti][stripe tj]
  {
    const size_t pBase = ((size_t)b * NN + rowBase) * (size_t)NN + colBase;
#pragma unroll
    for (int i = 0; i < 8; ++i) {
      const int c = i * 256 + t;  // 2048 chunks of 16B
      const int row = c >> 4;
      const int ck = c & 15;
      *(uint4*)(P + pBase + (size_t)row * NN + ck * 8) =
          *(const uint4*)(Pt + row * 128 + ((ck ^ (row & 7)) << 3));
    }
  }
  if (offdiag) {
    // mirrored store: P[b][stripe tj][stripe ti]
    const size_t pBase = ((size_t)b * NN + colBase) * (size_t)NN + rowBase;
#pragma unroll
    for (int i = 0; i < 8; ++i) {
      const int c = i * 256 + t;
      const int row = c >> 4;
      const int ck = c & 15;
      *(uint4*)(P + pBase + (size_t)row * NN + ck * 8) =
          *(const uint4*)(Mt + row * 128 + ((ck ^ (row & 7)) << 3));
    }
  }
}

// ---------------- GEMM2: O = P·V ; 128x192 tiles -> 512 blocks = exactly 2/CU (one round) ----------------
__global__ __launch_bounds__(256) void gemm_pv_kernel(
    const __hip_bfloat16* __restrict__ P,    // [B][N][N]
    const __hip_bfloat16* __restrict__ Vt,   // [B][D][N]
    const float* __restrict__ lsum,
    const float* __restrict__ conf,
    const float* __restrict__ F,             // [B][N][D] fp32
    float* __restrict__ Out) {
  __shared__ __hip_bfloat16 smem[2 * (128 * 64 + 192 * 64)];  // 80 KB -> 2 blocks/CU = 160 KB exactly

  const int d = blockIdx.x;                  // 0..511
  const int work = (d & 7) * 64 + (d >> 3);  // XCD k <- batch k (Vt batch 3 MB fits XCD L2)
  const int b = work >> 6;
  const int w6 = work & 63;
  const int colBase = (w6 & 3) * 192;        // over D (4 tiles of 192)
  const int rowBase = (w6 >> 2) * 128;       // over N (16 tiles of 128)

  const int t = threadIdx.x;
  const int lane = t & 63;
  const int wave = t >> 6;
  const int wRow = wave >> 1;
  const int wCol = wave & 1;
  const int quad = lane >> 4;
  const int l16 = lane & 15;

  const __hip_bfloat16* Abase = P + (size_t)b * NN * NN + (size_t)rowBase * NN;
  const __hip_bfloat16* Bbase = Vt + (size_t)b * DD * NN + (size_t)colBase * NN;

  // staging slots: A = 128x64 (1024 chunks of 16B), B = 192x64 (1536 chunks)
  int srowA[4], scolA[4], sc8A[4];
#pragma unroll
  for (int i = 0; i < 4; ++i) {
    const int c = i * 256 + t;
    srowA[i] = c >> 3;
    scolA[i] = ((c & 7) ^ ((c >> 3) & 7)) * 8;
    sc8A[i] = c * 8;
  }
  int srowB[6], scolB[6], sc8B[6];
#pragma unroll
  for (int i = 0; i < 6; ++i) {
    const int c = i * 256 + t;
    srowB[i] = c >> 3;
    scolB[i] = ((c & 7) ^ ((c >> 3) & 7)) * 8;
    sc8B[i] = c * 8;
  }

  f32x4 acc[4][6];
#pragma unroll
  for (int i = 0; i < 4; ++i)
#pragma unroll
    for (int j = 0; j < 6; ++j) acc[i][j] = (f32x4){0.f, 0.f, 0.f, 0.f};

  constexpr int ABUF = 128 * 64;             // 8192 elems
  constexpr int BUFSTRIDE = 128 * 64 + 192 * 64;  // 20480 elems

  {
    __hip_bfloat16* As = smem;
    __hip_bfloat16* Bs = smem + ABUF;
#pragma unroll
    for (int i = 0; i < 4; ++i)
      gload_lds16(Abase + (size_t)srowA[i] * NN + scolA[i], As + sc8A[i]);
#pragma unroll
    for (int i = 0; i < 6; ++i)
      gload_lds16(Bbase + (size_t)srowB[i] * NN + scolB[i], Bs + sc8B[i]);
  }

  constexpr int NK = NN / 64;  // 32
  for (int kk = 0; kk < NK; ++kk) {
    const int cur = kk & 1;
    __syncthreads();
    if (kk + 1 < NK) {
      __hip_bfloat16* As = smem + (1 - cur) * BUFSTRIDE;
      __hip_bfloat16* Bs = As + ABUF;
      const int k0 = (kk + 1) * 64;
#pragma unroll
      for (int i = 0; i < 4; ++i)
        gload_lds16(Abase + (size_t)srowA[i] * NN + (k0 + scolA[i]), As + sc8A[i]);
#pragma unroll
      for (int i = 0; i < 6; ++i)
        gload_lds16(Bbase + (size_t)srowB[i] * NN + (k0 + scolB[i]), Bs + sc8B[i]);
    }
    const __hip_bfloat16* As = smem + cur * BUFSTRIDE;
    const __hip_bfloat16* Bs = As + ABUF;
#pragma unroll
    for (int ks = 0; ks < 2; ++ks) {
      bf16x8 af[4], bfr[6];
#pragma unroll
      for (int i = 0; i < 4; ++i) {
        const int rA = wRow * 64 + i * 16 + l16;
        const int pA = (ks * 4 + quad) ^ (rA & 7);
        af[i] = *(const bf16x8*)(As + rA * 64 + pA * 8);
      }
#pragma unroll
      for (int i = 0; i < 6; ++i) {
        const int rB = wCol * 96 + i * 16 + l16;
        const int pB = (ks * 4 + quad) ^ (rB & 7);
        bfr[i] = *(const bf16x8*)(Bs + rB * 64 + pB * 8);
      }
#pragma unroll
      for (int mi = 0; mi < 4; ++mi)
#pragma unroll
        for (int ni = 0; ni < 6; ++ni)
          acc[mi][ni] = __builtin_amdgcn_mfma_f32_16x16x32_bf16(af[mi], bfr[ni], acc[mi][ni], 0, 0, 0);
    }
  }

#pragma unroll
  for (int mi = 0; mi < 4; ++mi) {
#pragma unroll
    for (int r = 0; r < 4; ++r) {
      const int row_g = rowBase + wRow * 64 + mi * 16 + quad * 4 + r;
      const float li = lsum[(size_t)b * NN + row_g];
      const float cw = conf[(size_t)b * NN + row_g];
      const float inv = 1.0f / li;   // li >= 1 (diag contributes exp(0)=1)
      const float* frow = F + ((size_t)b * NN + row_g) * DD;
      float* orow = Out + ((size_t)b * NN + row_g) * DD;
#pragma unroll
      for (int ni = 0; ni < 6; ++ni) {
        const int col_g = colBase + wCol * 96 + ni * 16 + l16;
        const float o = acc[mi][ni][r] * inv;
        orow[col_g] = cw * o + (1.f - cw) * frow[col_g];
      }
    }
  }
}

extern "C" void kernel_launch(void* const* d_in, const int* in_sizes, int n_in,
                              void* d_out, int out_size, void* d_ws, size_t ws_size,
                              hipStream_t stream) {
  const float* F = (const float*)d_in[0];   // final_features
  const float* M = (const float*)d_in[1];   // mid_features
  float* Out = (float*)d_out;

  char* ws = (char*)d_ws;
  // layout: Qn (25165824) | Vt (25165824) | P (67108864) | lsum (65536) | conf (65536)
  __hip_bfloat16* Qn = (__hip_bfloat16*)(ws);
  __hip_bfloat16* Vt = (__hip_bfloat16*)(ws + 25165824);
  __hip_bfloat16* P  = (__hip_bfloat16*)(ws + 50331648);
  float* lsum        = (float*)(ws + 117440512);
  float* conf        = (float*)(ws + 117506048);

  prep_kernel<<<NORM_BLOCKS, 256, 0, stream>>>(M, Qn, lsum, conf);
  gemm_qk_kernel<<<QK_BLOCKS + TRANS_BLOCKS, 256, 0, stream>>>(Qn, P, lsum, (unsigned*)conf, F, Vt);
  gemm_pv_kernel<<<512, 256, 0, stream>>>(P, Vt, lsum, conf, F, Out);
}

// Round 3
// 254.860 us; speedup vs baseline: 1.0457x; 1.0156x over previous
//
#include <hip/hip_runtime.h>
#include <hip/hip_bf16.h>

// Problem constants (setup_inputs: B=8, N=2048, D=768, fp32)
static constexpr int BB = 8;
static constexpr int NN = 2048;
static constexpr int DD = 768;

typedef __attribute__((ext_vector_type(8))) __bf16 bf16x8;
typedef __attribute__((ext_vector_type(4))) float f32x4;

__device__ __forceinline__ void gload_lds16(const __hip_bfloat16* g, __hip_bfloat16* l) {
  __builtin_amdgcn_global_load_lds(
      (const __attribute__((address_space(1))) void*)g,
      (__attribute__((address_space(3))) void*)l,
      16, 0, 0);
}

// ---------------- prep: normalize mid -> Qn bf16 (+zero lsum/conf), transpose F -> Vt bf16 ----------------
static constexpr int NORM_BLOCKS = (BB * NN) / 4;                 // 4096
static constexpr int TRANS_BLOCKS = BB * (NN / 64) * (DD / 64);   // 8*32*12 = 3072
static constexpr int QK_BLOCKS = BB * 136;                        // 1088

__global__ void prep_kernel(const float* __restrict__ mid, __hip_bfloat16* __restrict__ Qn,
                            float* __restrict__ lsum, float* __restrict__ conf,
                            const float* __restrict__ F, __hip_bfloat16* __restrict__ Vt) {
  // bf16 tile, 8.7 KB (row stride 68 keeps ushort4 rows 8B-aligned) -> prep occupancy
  // stays at the 8-block/CU wave cap for BOTH norm and transpose blocks.
  __shared__ __hip_bfloat16 tile[64][68];
  const int t = threadIdx.x;
  if (blockIdx.x < NORM_BLOCKS) {
    const int wave = t >> 6;
    const int lane = t & 63;
    const size_t row = (size_t)blockIdx.x * 4 + wave;
    if (lane == 0) { lsum[row] = 0.f; conf[row] = 0.f; }
    const float* src = mid + row * DD;

    float4 v[3];
    float ss = 0.f;
#pragma unroll
    for (int j = 0; j < 3; ++j) {
      v[j] = *(const float4*)(src + j * 256 + lane * 4);
      ss += v[j].x * v[j].x + v[j].y * v[j].y + v[j].z * v[j].z + v[j].w * v[j].w;
    }
#pragma unroll
    for (int o = 32; o; o >>= 1) ss += __shfl_xor(ss, o, 64);
    const float inv = 1.0f / fmaxf(sqrtf(ss), 1e-12f);

    __hip_bfloat16* dst = Qn + row * DD;
#pragma unroll
    for (int j = 0; j < 3; ++j) {
      union { ushort4 u; __hip_bfloat16 h[4]; } pk;
      pk.h[0] = __float2bfloat16(v[j].x * inv);
      pk.h[1] = __float2bfloat16(v[j].y * inv);
      pk.h[2] = __float2bfloat16(v[j].z * inv);
      pk.h[3] = __float2bfloat16(v[j].w * inv);
      *(ushort4*)(dst + j * 256 + lane * 4) = pk.u;
    }
  } else {
    // ---- vectorized transpose: F[b][n][d] fp32 -> Vt[b][d][n] bf16, 64x64 tiles ----
    const int bid = blockIdx.x - NORM_BLOCKS;
    const int bx = bid % (DD / 64);         // d-tile 0..11
    const int rest = bid / (DD / 64);
    const int by = rest & 31;               // n-tile 0..31
    const int b = rest >> 5;
    const int n0 = by * 64;
    const int d0 = bx * 64;
    const int tr = t >> 4;                  // 0..15
    const int tc = t & 15;                  // 0..15
#pragma unroll
    for (int i = 0; i < 4; ++i) {
      const int n = tr + i * 16;
      const float4 v = *(const float4*)(F + ((size_t)b * NN + n0 + n) * DD + d0 + tc * 4);
      union { ushort4 u; __hip_bfloat16 h[4]; } pk;
      pk.h[0] = __float2bfloat16(v.x);
      pk.h[1] = __float2bfloat16(v.y);
      pk.h[2] = __float2bfloat16(v.z);
      pk.h[3] = __float2bfloat16(v.w);
      *(ushort4*)&tile[n][tc * 4] = pk.u;   // 136B row stride -> 8B aligned
    }
    __syncthreads();
#pragma unroll
    for (int i = 0; i < 4; ++i) {
      const int dd = tr + i * 16;           // local d
      const int n4 = tc * 4;                // local n base
      union { ushort4 u; __hip_bfloat16 h[4]; } pk;
#pragma unroll
      for (int j = 0; j < 4; ++j) pk.h[j] = tile[n4 + j][dd];
      *(ushort4*)(Vt + ((size_t)b * DD + d0 + dd) * NN + n0 + n4) = pk.u;
    }
  }
}

// ---------------- GEMM1 (symmetric): S = Qn·Qnᵀ, upper-triangle tiles only ----------------
// Off-diag tiles scheduled first, diagonal tiles (lighter epilogue) in the tail round.
__global__ __launch_bounds__(256) void gemm_qk_kernel(
    const __hip_bfloat16* __restrict__ Qn,
    __hip_bfloat16* __restrict__ P,
    float* __restrict__ lsum,
    unsigned* __restrict__ conf) {
  __shared__ __hip_bfloat16 smem[4 * 128 * 64];  // 64 KB: dbuf staging; epilogue: Pt(32K)+Mt(32K)
  const int t = threadIdx.x;

  const int d = blockIdx.x;                // 0..1087 (8 batches x 136 triangle tiles)
  const int b = d & 7;                     // XCD k <- batch k (Qn batch 3 MB fits XCD L2)
  int rem = d >> 3;                        // 0..135
  int ti, tj;
  if (rem < 120) {                         // strict upper triangle (i<j), 120 pairs
    ti = 0;
    while (rem >= 15 - ti) { rem -= 15 - ti; ++ti; }
    tj = ti + 1 + rem;
  } else {                                 // 16 diagonal tiles, scheduled last
    ti = tj = rem - 120;
  }
  const int rowBase = ti * 128;
  const int colBase = tj * 128;
  const bool offdiag = (ti != tj);

  const int lane = t & 63;
  const int wave = t >> 6;
  const int wRow = wave >> 1;
  const int wCol = wave & 1;
  const int quad = lane >> 4;
  const int l16 = lane & 15;

  const __hip_bfloat16* Abase = Qn + ((size_t)b * NN + rowBase) * DD;
  const __hip_bfloat16* Bbase = Qn + ((size_t)b * NN + colBase) * DD;

  // staging slots (lane-contiguous dest for global_load_lds; source XOR-swizzled)
  int srow[4], scol[4], sc8[4];
#pragma unroll
  for (int i = 0; i < 4; ++i) {
    const int c = i * 256 + t;
    srow[i] = c >> 3;
    const int col8 = (c & 7) ^ ((c >> 3) & 7);
    scol[i] = col8 * 8;
    sc8[i] = c * 8;
  }

  f32x4 acc[4][4];
#pragma unroll
  for (int i = 0; i < 4; ++i)
#pragma unroll
    for (int j = 0; j < 4; ++j) acc[i][j] = (f32x4){0.f, 0.f, 0.f, 0.f};

  // prologue: stage tile 0 into buf 0
  {
    __hip_bfloat16* As = smem;
    __hip_bfloat16* Bs = smem + 128 * 64;
#pragma unroll
    for (int i = 0; i < 4; ++i) {
      gload_lds16(Abase + (size_t)srow[i] * DD + scol[i], As + sc8[i]);
      gload_lds16(Bbase + (size_t)srow[i] * DD + scol[i], Bs + sc8[i]);
    }
  }

  constexpr int NK = DD / 64;  // 12
  for (int kk = 0; kk < NK; ++kk) {
    const int cur = kk & 1;
    __syncthreads();  // buf[cur] staged; buf[1-cur] consumed
    if (kk + 1 < NK) {
      __hip_bfloat16* As = smem + (1 - cur) * 2 * 128 * 64;
      __hip_bfloat16* Bs = As + 128 * 64;
      const int k0 = (kk + 1) * 64;
#pragma unroll
      for (int i = 0; i < 4; ++i) {
        gload_lds16(Abase + (size_t)srow[i] * DD + (k0 + scol[i]), As + sc8[i]);
        gload_lds16(Bbase + (size_t)srow[i] * DD + (k0 + scol[i]), Bs + sc8[i]);
      }
    }
    const __hip_bfloat16* As = smem + cur * 2 * 128 * 64;
    const __hip_bfloat16* Bs = As + 128 * 64;
#pragma unroll
    for (int ks = 0; ks < 2; ++ks) {
      bf16x8 af[4], bfr[4];
#pragma unroll
      for (int i = 0; i < 4; ++i) {
        const int rA = wRow * 64 + i * 16 + l16;
        const int rB = wCol * 64 + i * 16 + l16;
        const int pA = (ks * 4 + quad) ^ (rA & 7);
        const int pB = (ks * 4 + quad) ^ (rB & 7);
        af[i]  = *(const bf16x8*)(As + rA * 64 + pA * 8);
        bfr[i] = *(const bf16x8*)(Bs + rB * 64 + pB * 8);
      }
#pragma unroll
      for (int mi = 0; mi < 4; ++mi)
#pragma unroll
        for (int ni = 0; ni < 4; ++ni)
          acc[mi][ni] = __builtin_amdgcn_mfma_f32_16x16x32_bf16(af[mi], bfr[ni], acc[mi][ni], 0, 0, 0);
    }
  }

  __syncthreads();  // K-loop LDS reads done; reuse smem as Pt + Mt (XOR-swizzled)
  __hip_bfloat16* Pt = smem;              // direct tile  [128][128]
  __hip_bfloat16* Mt = smem + 128 * 128;  // mirror tile  [128][128]

  float csum[4] = {0.f, 0.f, 0.f, 0.f};
  float cmax[4] = {0.f, 0.f, 0.f, 0.f};  // clamp at 0 valid (diag of full matrix is 0)

#pragma unroll
  for (int mi = 0; mi < 4; ++mi) {
    const int rbase = wRow * 64 + mi * 16 + quad * 4;
    float rs[4] = {0.f, 0.f, 0.f, 0.f};
    float rm[4] = {0.f, 0.f, 0.f, 0.f};
#pragma unroll
    for (int ni = 0; ni < 4; ++ni) {
      const int colL = wCol * 64 + ni * 16 + l16;
      const int col_g = colBase + colL;
      union { ushort4 u; __hip_bfloat16 h[4]; } pk;
#pragma unroll
      for (int r = 0; r < 4; ++r) {
        const int rowL = rbase + r;
        float s = acc[mi][ni][r];
        if (rowBase + rowL == col_g) s = 0.f;   // only possible on diagonal tiles
        const float p = __expf(s);              // T=1; |s|<=1 so no max-subtraction needed
        rm[r] = fmaxf(rm[r], s);
        rs[r] += p;
        csum[ni] += p;
        cmax[ni] = fmaxf(cmax[ni], s);
        pk.h[r] = __float2bfloat16(p);
        Pt[rowL * 128 + (((colL >> 3) ^ (rowL & 7)) << 3) + (colL & 7)] = pk.h[r];
      }
      if (offdiag) {  // mirror: Mt[colL][rbase..rbase+3] (8B-aligned: rbase%4==0, rbase&7 in {0,4})
        *(ushort4*)(Mt + colL * 128 + (((rbase >> 3) ^ (colL & 7)) << 3) + (rbase & 7)) = pk.u;
      }
    }
#pragma unroll
    for (int r = 0; r < 4; ++r) {
      float ps = rs[r], mx = rm[r];
#pragma unroll
      for (int o = 1; o < 16; o <<= 1) {
        ps += __shfl_xor(ps, o, 64);
        mx = fmaxf(mx, __shfl_xor(mx, o, 64));
      }
      if (l16 == 0) {
        const int row_g = rowBase + rbase + r;
        atomicAdd(lsum + (size_t)b * NN + row_g, ps);
        atomicMax(conf + (size_t)b * NN + row_g, __float_as_uint(mx));  // nonneg: uint order == float order
      }
    }
  }

  // column stats -> stripe tj rows (mirror contribution), off-diag only
  if (offdiag) {
#pragma unroll
    for (int ni = 0; ni < 4; ++ni) {
      float cs = csum[ni];
      float cm = cmax[ni];
      cs += __shfl_xor(cs, 16, 64); cm = fmaxf(cm, __shfl_xor(cm, 16, 64));
      cs += __shfl_xor(cs, 32, 64); cm = fmaxf(cm, __shfl_xor(cm, 32, 64));
      if (quad == 0) {
        const int col_g = colBase + wCol * 64 + ni * 16 + l16;
        atomicAdd(lsum + (size_t)b * NN + col_g, cs);
        atomicMax(conf + (size_t)b * NN + col_g, __float_as_uint(cm));
      }
    }
  }

  __syncthreads();
  // direct store: P[b][stripe ti][stripe tj]
  {
    const size_t pBase = ((size_t)b * NN + rowBase) * (size_t)NN + colBase;
#pragma unroll
    for (int i = 0; i < 8; ++i) {
      const int c = i * 256 + t;  // 2048 chunks of 16B
      const int row = c >> 4;
      const int ck = c & 15;
      *(uint4*)(P + pBase + (size_t)row * NN + ck * 8) =
          *(const uint4*)(Pt + row * 128 + ((ck ^ (row & 7)) << 3));
    }
  }
  if (offdiag) {
    // mirrored store: P[b][stripe tj][stripe ti]
    const size_t pBase = ((size_t)b * NN + colBase) * (size_t)NN + rowBase;
#pragma unroll
    for (int i = 0; i < 8; ++i) {
      const int c = i * 256 + t;
      const int row = c >> 4;
      const int ck = c & 15;
      *(uint4*)(P + pBase + (size_t)row * NN + ck * 8) =
          *(const uint4*)(Mt + row * 128 + ((ck ^ (row & 7)) << 3));
    }
  }
}

// ---------------- GEMM2: O = P·V ; 128x192 tiles -> 512 blocks = exactly 2/CU (one round) ----------------
__global__ __launch_bounds__(256) void gemm_pv_kernel(
    const __hip_bfloat16* __restrict__ P,    // [B][N][N]
    const __hip_bfloat16* __restrict__ Vt,   // [B][D][N]
    const float* __restrict__ lsum,
    const float* __restrict__ conf,
    const float* __restrict__ F,             // [B][N][D] fp32
    float* __restrict__ Out) {
  __shared__ __hip_bfloat16 smem[2 * (128 * 64 + 192 * 64)];  // 80 KB -> 2 blocks/CU = 160 KB exactly

  const int d = blockIdx.x;                  // 0..511
  const int work = (d & 7) * 64 + (d >> 3);  // XCD k <- batch k (Vt batch 3 MB fits XCD L2)
  const int b = work >> 6;
  const int w6 = work & 63;
  const int colBase = (w6 & 3) * 192;        // over D (4 tiles of 192)
  const int rowBase = (w6 >> 2) * 128;       // over N (16 tiles of 128)

  const int t = threadIdx.x;
  const int lane = t & 63;
  const int wave = t >> 6;
  const int wRow = wave >> 1;
  const int wCol = wave & 1;
  const int quad = lane >> 4;
  const int l16 = lane & 15;

  const __hip_bfloat16* Abase = P + (size_t)b * NN * NN + (size_t)rowBase * NN;
  const __hip_bfloat16* Bbase = Vt + (size_t)b * DD * NN + (size_t)colBase * NN;

  // staging slots: A = 128x64 (1024 chunks of 16B), B = 192x64 (1536 chunks)
  int srowA[4], scolA[4], sc8A[4];
#pragma unroll
  for (int i = 0; i < 4; ++i) {
    const int c = i * 256 + t;
    srowA[i] = c >> 3;
    scolA[i] = ((c & 7) ^ ((c >> 3) & 7)) * 8;
    sc8A[i] = c * 8;
  }
  int srowB[6], scolB[6], sc8B[6];
#pragma unroll
  for (int i = 0; i < 6; ++i) {
    const int c = i * 256 + t;
    srowB[i] = c >> 3;
    scolB[i] = ((c & 7) ^ ((c >> 3) & 7)) * 8;
    sc8B[i] = c * 8;
  }

  f32x4 acc[4][6];
#pragma unroll
  for (int i = 0; i < 4; ++i)
#pragma unroll
    for (int j = 0; j < 6; ++j) acc[i][j] = (f32x4){0.f, 0.f, 0.f, 0.f};

  constexpr int ABUF = 128 * 64;             // 8192 elems
  constexpr int BUFSTRIDE = 128 * 64 + 192 * 64;  // 20480 elems

  {
    __hip_bfloat16* As = smem;
    __hip_bfloat16* Bs = smem + ABUF;
#pragma unroll
    for (int i = 0; i < 4; ++i)
      gload_lds16(Abase + (size_t)srowA[i] * NN + scolA[i], As + sc8A[i]);
#pragma unroll
    for (int i = 0; i < 6; ++i)
      gload_lds16(Bbase + (size_t)srowB[i] * NN + scolB[i], Bs + sc8B[i]);
  }

  constexpr int NK = NN / 64;  // 32
  for (int kk = 0; kk < NK; ++kk) {
    const int cur = kk & 1;
    __syncthreads();
    if (kk + 1 < NK) {
      __hip_bfloat16* As = smem + (1 - cur) * BUFSTRIDE;
      __hip_bfloat16* Bs = As + ABUF;
      const int k0 = (kk + 1) * 64;
#pragma unroll
      for (int i = 0; i < 4; ++i)
        gload_lds16(Abase + (size_t)srowA[i] * NN + (k0 + scolA[i]), As + sc8A[i]);
#pragma unroll
      for (int i = 0; i < 6; ++i)
        gload_lds16(Bbase + (size_t)srowB[i] * NN + (k0 + scolB[i]), Bs + sc8B[i]);
    }
    const __hip_bfloat16* As = smem + cur * BUFSTRIDE;
    const __hip_bfloat16* Bs = As + ABUF;
#pragma unroll
    for (int ks = 0; ks < 2; ++ks) {
      bf16x8 af[4], bfr[6];
#pragma unroll
      for (int i = 0; i < 4; ++i) {
        const int rA = wRow * 64 + i * 16 + l16;
        const int pA = (ks * 4 + quad) ^ (rA & 7);
        af[i] = *(const bf16x8*)(As + rA * 64 + pA * 8);
      }
#pragma unroll
      for (int i = 0; i < 6; ++i) {
        const int rB = wCol * 96 + i * 16 + l16;
        const int pB = (ks * 4 + quad) ^ (rB & 7);
        bfr[i] = *(const bf16x8*)(Bs + rB * 64 + pB * 8);
      }
#pragma unroll
      for (int mi = 0; mi < 4; ++mi)
#pragma unroll
        for (int ni = 0; ni < 6; ++ni)
          acc[mi][ni] = __builtin_amdgcn_mfma_f32_16x16x32_bf16(af[mi], bfr[ni], acc[mi][ni], 0, 0, 0);
    }
  }

#pragma unroll
  for (int mi = 0; mi < 4; ++mi) {
#pragma unroll
    for (int r = 0; r < 4; ++r) {
      const int row_g = rowBase + wRow * 64 + mi * 16 + quad * 4 + r;
      const float li = lsum[(size_t)b * NN + row_g];
      const float cw = conf[(size_t)b * NN + row_g];
      const float inv = 1.0f / li;   // li >= 1 (diag contributes exp(0)=1)
      const float* frow = F + ((size_t)b * NN + row_g) * DD;
      float* orow = Out + ((size_t)b * NN + row_g) * DD;
#pragma unroll
      for (int ni = 0; ni < 6; ++ni) {
        const int col_g = colBase + wCol * 96 + ni * 16 + l16;
        const float o = acc[mi][ni][r] * inv;
        orow[col_g] = cw * o + (1.f - cw) * frow[col_g];
      }
    }
  }
}

extern "C" void kernel_launch(void* const* d_in, const int* in_sizes, int n_in,
                              void* d_out, int out_size, void* d_ws, size_t ws_size,
                              hipStream_t stream) {
  const float* F = (const float*)d_in[0];   // final_features
  const float* M = (const float*)d_in[1];   // mid_features
  float* Out = (float*)d_out;

  char* ws = (char*)d_ws;
  // layout: Qn (25165824) | Vt (25165824) | P (67108864) | lsum (65536) | conf (65536)
  __hip_bfloat16* Qn = (__hip_bfloat16*)(ws);
  __hip_bfloat16* Vt = (__hip_bfloat16*)(ws + 25165824);
  __hip_bfloat16* P  = (__hip_bfloat16*)(ws + 50331648);
  float* lsum        = (float*)(ws + 117440512);
  float* conf        = (float*)(ws + 117506048);

  prep_kernel<<<NORM_BLOCKS + TRANS_BLOCKS, 256, 0, stream>>>(M, Qn, lsum, conf, F, Vt);
  gemm_qk_kernel<<<QK_BLOCKS, 256, 0, stream>>>(Qn, P, lsum, (unsigned*)conf);
  gemm_pv_kernel<<<512, 256, 0, stream>>>(P, Vt, lsum, conf, F, Out);
}

// Round 4
// 251.132 us; speedup vs baseline: 1.0612x; 1.0148x over previous
//
#include <hip/hip_runtime.h>
#include <hip/hip_bf16.h>

// Problem constants (setup_inputs: B=8, N=2048, D=768, fp32)
static constexpr int BB = 8;
static constexpr int NN = 2048;
static constexpr int DD = 768;

typedef __attribute__((ext_vector_type(8))) __bf16 bf16x8;
typedef __attribute__((ext_vector_type(4))) float f32x4;

__device__ __forceinline__ void gload_lds16(const __hip_bfloat16* g, __hip_bfloat16* l) {
  __builtin_amdgcn_global_load_lds(
      (const __attribute__((address_space(1))) void*)g,
      (__attribute__((address_space(3))) void*)l,
      16, 0, 0);
}

// ---------------- prep: normalize mid -> Qn bf16 (+zero lsum/conf), transpose F -> Vt bf16 ----------------
static constexpr int NORM_BLOCKS = (BB * NN) / 4;                 // 4096
static constexpr int TRANS_BLOCKS = BB * (NN / 64) * (DD / 64);   // 8*32*12 = 3072
static constexpr int QK_BLOCKS = BB * 136;                        // 1088

__global__ void prep_kernel(const float* __restrict__ mid, __hip_bfloat16* __restrict__ Qn,
                            float* __restrict__ lsum, float* __restrict__ conf,
                            const float* __restrict__ F, __hip_bfloat16* __restrict__ Vt) {
  // bf16 tile, 8.7 KB (row stride 68 keeps ushort4 rows 8B-aligned) -> prep occupancy
  // stays at the 8-block/CU wave cap for BOTH norm and transpose blocks.
  __shared__ __hip_bfloat16 tile[64][68];
  const int t = threadIdx.x;
  if (blockIdx.x < NORM_BLOCKS) {
    const int wave = t >> 6;
    const int lane = t & 63;
    const size_t row = (size_t)blockIdx.x * 4 + wave;
    if (lane == 0) { lsum[row] = 0.f; conf[row] = 0.f; }
    const float* src = mid + row * DD;

    float4 v[3];
    float ss = 0.f;
#pragma unroll
    for (int j = 0; j < 3; ++j) {
      v[j] = *(const float4*)(src + j * 256 + lane * 4);
      ss += v[j].x * v[j].x + v[j].y * v[j].y + v[j].z * v[j].z + v[j].w * v[j].w;
    }
#pragma unroll
    for (int o = 32; o; o >>= 1) ss += __shfl_xor(ss, o, 64);
    const float inv = 1.0f / fmaxf(sqrtf(ss), 1e-12f);

    __hip_bfloat16* dst = Qn + row * DD;
#pragma unroll
    for (int j = 0; j < 3; ++j) {
      union { ushort4 u; __hip_bfloat16 h[4]; } pk;
      pk.h[0] = __float2bfloat16(v[j].x * inv);
      pk.h[1] = __float2bfloat16(v[j].y * inv);
      pk.h[2] = __float2bfloat16(v[j].z * inv);
      pk.h[3] = __float2bfloat16(v[j].w * inv);
      *(ushort4*)(dst + j * 256 + lane * 4) = pk.u;
    }
  } else {
    // ---- vectorized transpose: F[b][n][d] fp32 -> Vt[b][d][n] bf16, 64x64 tiles ----
    const int bid = blockIdx.x - NORM_BLOCKS;
    const int bx = bid % (DD / 64);         // d-tile 0..11
    const int rest = bid / (DD / 64);
    const int by = rest & 31;               // n-tile 0..31
    const int b = rest >> 5;
    const int n0 = by * 64;
    const int d0 = bx * 64;
    const int tr = t >> 4;                  // 0..15
    const int tc = t & 15;                  // 0..15
#pragma unroll
    for (int i = 0; i < 4; ++i) {
      const int n = tr + i * 16;
      const float4 v = *(const float4*)(F + ((size_t)b * NN + n0 + n) * DD + d0 + tc * 4);
      union { ushort4 u; __hip_bfloat16 h[4]; } pk;
      pk.h[0] = __float2bfloat16(v.x);
      pk.h[1] = __float2bfloat16(v.y);
      pk.h[2] = __float2bfloat16(v.z);
      pk.h[3] = __float2bfloat16(v.w);
      *(ushort4*)&tile[n][tc * 4] = pk.u;   // 136B row stride -> 8B aligned
    }
    __syncthreads();
#pragma unroll
    for (int i = 0; i < 4; ++i) {
      const int dd = tr + i * 16;           // local d
      const int n4 = tc * 4;                // local n base
      union { ushort4 u; __hip_bfloat16 h[4]; } pk;
#pragma unroll
      for (int j = 0; j < 4; ++j) pk.h[j] = tile[n4 + j][dd];
      *(ushort4*)(Vt + ((size_t)b * DD + d0 + dd) * NN + n0 + n4) = pk.u;
    }
  }
}

// ---------------- GEMM1 (symmetric): S = Qn·Qnᵀ, upper-triangle tiles only ----------------
// 32 KB LDS (single-buffered staging, no epilogue LDS) -> 3-4 blocks/CU.
// Epilogue stores BOTH P tiles directly from registers:
//   direct tile : scalar 2B stores, 16 consecutive lanes = 32B runs per row
//   mirror tile : lane's 4 r-values = 4 consecutive cols -> ushort4 (8B), quads tile 32B runs
__global__ __launch_bounds__(256, 3) void gemm_qk_kernel(
    const __hip_bfloat16* __restrict__ Qn,
    __hip_bfloat16* __restrict__ P,
    float* __restrict__ lsum,
    unsigned* __restrict__ conf) {
  __shared__ __hip_bfloat16 smem[2 * 128 * 64];  // 32 KB: As(16K) + Bs(16K), single-buffered
  const int t = threadIdx.x;

  const int d = blockIdx.x;                // 0..1087 (8 batches x 136 triangle tiles)
  const int b = d & 7;                     // XCD k <- batch k (Qn batch 3 MB fits XCD L2)
  int rem = d >> 3;                        // 0..135
  int ti, tj;
  if (rem < 120) {                         // strict upper triangle (i<j), 120 pairs
    ti = 0;
    while (rem >= 15 - ti) { rem -= 15 - ti; ++ti; }
    tj = ti + 1 + rem;
  } else {                                 // 16 diagonal tiles, scheduled last
    ti = tj = rem - 120;
  }
  const int rowBase = ti * 128;
  const int colBase = tj * 128;
  const bool offdiag = (ti != tj);

  const int lane = t & 63;
  const int wave = t >> 6;
  const int wRow = wave >> 1;
  const int wCol = wave & 1;
  const int quad = lane >> 4;
  const int l16 = lane & 15;

  const __hip_bfloat16* Abase = Qn + ((size_t)b * NN + rowBase) * DD;
  const __hip_bfloat16* Bbase = Qn + ((size_t)b * NN + colBase) * DD;

  // staging slots (lane-contiguous dest for global_load_lds; source XOR-swizzled)
  int srow[4], scol[4], sc8[4];
#pragma unroll
  for (int i = 0; i < 4; ++i) {
    const int c = i * 256 + t;
    srow[i] = c >> 3;
    const int col8 = (c & 7) ^ ((c >> 3) & 7);
    scol[i] = col8 * 8;
    sc8[i] = c * 8;
  }

  f32x4 acc[4][4];
#pragma unroll
  for (int i = 0; i < 4; ++i)
#pragma unroll
    for (int j = 0; j < 4; ++j) acc[i][j] = (f32x4){0.f, 0.f, 0.f, 0.f};

  __hip_bfloat16* As = smem;
  __hip_bfloat16* Bs = smem + 128 * 64;

  // prologue: stage tile 0
#pragma unroll
  for (int i = 0; i < 4; ++i) {
    gload_lds16(Abase + (size_t)srow[i] * DD + scol[i], As + sc8[i]);
    gload_lds16(Bbase + (size_t)srow[i] * DD + scol[i], Bs + sc8[i]);
  }

  constexpr int NK = DD / 64;  // 12
  for (int kk = 0; kk < NK; ++kk) {
    __syncthreads();  // staged data visible (compiler drains vmcnt before barrier)
#pragma unroll
    for (int ks = 0; ks < 2; ++ks) {
      bf16x8 af[4], bfr[4];
#pragma unroll
      for (int i = 0; i < 4; ++i) {
        const int rA = wRow * 64 + i * 16 + l16;
        const int rB = wCol * 64 + i * 16 + l16;
        const int pA = (ks * 4 + quad) ^ (rA & 7);
        const int pB = (ks * 4 + quad) ^ (rB & 7);
        af[i]  = *(const bf16x8*)(As + rA * 64 + pA * 8);
        bfr[i] = *(const bf16x8*)(Bs + rB * 64 + pB * 8);
      }
#pragma unroll
      for (int mi = 0; mi < 4; ++mi)
#pragma unroll
        for (int ni = 0; ni < 4; ++ni)
          acc[mi][ni] = __builtin_amdgcn_mfma_f32_16x16x32_bf16(af[mi], bfr[ni], acc[mi][ni], 0, 0, 0);
    }
    if (kk + 1 < NK) {
      __syncthreads();  // all waves done reading buf
      const int k0 = (kk + 1) * 64;
#pragma unroll
      for (int i = 0; i < 4; ++i) {
        gload_lds16(Abase + (size_t)srow[i] * DD + (k0 + scol[i]), As + sc8[i]);
        gload_lds16(Bbase + (size_t)srow[i] * DD + (k0 + scol[i]), Bs + sc8[i]);
      }
    }
  }

  // ---- epilogue: stats + direct-from-register P stores (no LDS, no barriers) ----
  __hip_bfloat16* Pdir = P + ((size_t)b * NN + rowBase) * NN + colBase;  // [row][col]
  __hip_bfloat16* Pmir = P + ((size_t)b * NN + colBase) * NN + rowBase;  // [col][row]

  float csum[4] = {0.f, 0.f, 0.f, 0.f};
  float cmax[4] = {0.f, 0.f, 0.f, 0.f};  // clamp at 0 valid (diag of full matrix is 0)

#pragma unroll
  for (int mi = 0; mi < 4; ++mi) {
    const int rbase = wRow * 64 + mi * 16 + quad * 4;
    float rs[4] = {0.f, 0.f, 0.f, 0.f};
    float rm[4] = {0.f, 0.f, 0.f, 0.f};
#pragma unroll
    for (int ni = 0; ni < 4; ++ni) {
      const int colL = wCol * 64 + ni * 16 + l16;
      const int col_g = colBase + colL;
      union { ushort4 u; __hip_bfloat16 h[4]; } pk;
#pragma unroll
      for (int r = 0; r < 4; ++r) {
        const int rowL = rbase + r;
        float s = acc[mi][ni][r];
        if (rowBase + rowL == col_g) s = 0.f;   // only possible on diagonal tiles
        const float p = __expf(s);              // T=1; |s|<=1 so no max-subtraction needed
        rm[r] = fmaxf(rm[r], s);
        rs[r] += p;
        csum[ni] += p;
        cmax[ni] = fmaxf(cmax[ni], s);
        pk.h[r] = __float2bfloat16(p);
        Pdir[(size_t)rowL * NN + colL] = pk.h[r];           // scalar 2B store
      }
      if (offdiag) {  // mirror: 4 consecutive cols per lane -> 8B store (rbase%4==0)
        *(ushort4*)(Pmir + (size_t)colL * NN + rbase) = pk.u;
      }
    }
#pragma unroll
    for (int r = 0; r < 4; ++r) {
      float ps = rs[r], mx = rm[r];
#pragma unroll
      for (int o = 1; o < 16; o <<= 1) {
        ps += __shfl_xor(ps, o, 64);
        mx = fmaxf(mx, __shfl_xor(mx, o, 64));
      }
      if (l16 == 0) {
        const int row_g = rowBase + rbase + r;
        atomicAdd(lsum + (size_t)b * NN + row_g, ps);
        atomicMax(conf + (size_t)b * NN + row_g, __float_as_uint(mx));  // nonneg: uint order == float order
      }
    }
  }

  // column stats -> stripe tj rows (mirror contribution), off-diag only
  if (offdiag) {
#pragma unroll
    for (int ni = 0; ni < 4; ++ni) {
      float cs = csum[ni];
      float cm = cmax[ni];
      cs += __shfl_xor(cs, 16, 64); cm = fmaxf(cm, __shfl_xor(cm, 16, 64));
      cs += __shfl_xor(cs, 32, 64); cm = fmaxf(cm, __shfl_xor(cm, 32, 64));
      if (quad == 0) {
        const int col_g = colBase + wCol * 64 + ni * 16 + l16;
        atomicAdd(lsum + (size_t)b * NN + col_g, cs);
        atomicMax(conf + (size_t)b * NN + col_g, __float_as_uint(cm));
      }
    }
  }
}

// ---------------- GEMM2: O = P·V ; 128x192 tiles -> 512 blocks = exactly 2/CU (one round) ----------------
__global__ __launch_bounds__(256) void gemm_pv_kernel(
    const __hip_bfloat16* __restrict__ P,    // [B][N][N]
    const __hip_bfloat16* __restrict__ Vt,   // [B][D][N]
    const float* __restrict__ lsum,
    const float* __restrict__ conf,
    const float* __restrict__ F,             // [B][N][D] fp32
    float* __restrict__ Out) {
  __shared__ __hip_bfloat16 smem[2 * (128 * 64 + 192 * 64)];  // 80 KB -> 2 blocks/CU = 160 KB exactly

  const int d = blockIdx.x;                  // 0..511
  const int work = (d & 7) * 64 + (d >> 3);  // XCD k <- batch k (Vt batch 3 MB fits XCD L2)
  const int b = work >> 6;
  const int w6 = work & 63;
  const int colBase = (w6 & 3) * 192;        // over D (4 tiles of 192)
  const int rowBase = (w6 >> 2) * 128;       // over N (16 tiles of 128)

  const int t = threadIdx.x;
  const int lane = t & 63;
  const int wave = t >> 6;
  const int wRow = wave >> 1;
  const int wCol = wave & 1;
  const int quad = lane >> 4;
  const int l16 = lane & 15;

  const __hip_bfloat16* Abase = P + (size_t)b * NN * NN + (size_t)rowBase * NN;
  const __hip_bfloat16* Bbase = Vt + (size_t)b * DD * NN + (size_t)colBase * NN;

  // staging slots: A = 128x64 (1024 chunks of 16B), B = 192x64 (1536 chunks)
  int srowA[4], scolA[4], sc8A[4];
#pragma unroll
  for (int i = 0; i < 4; ++i) {
    const int c = i * 256 + t;
    srowA[i] = c >> 3;
    scolA[i] = ((c & 7) ^ ((c >> 3) & 7)) * 8;
    sc8A[i] = c * 8;
  }
  int srowB[6], scolB[6], sc8B[6];
#pragma unroll
  for (int i = 0; i < 6; ++i) {
    const int c = i * 256 + t;
    srowB[i] = c >> 3;
    scolB[i] = ((c & 7) ^ ((c >> 3) & 7)) * 8;
    sc8B[i] = c * 8;
  }

  f32x4 acc[4][6];
#pragma unroll
  for (int i = 0; i < 4; ++i)
#pragma unroll
    for (int j = 0; j < 6; ++j) acc[i][j] = (f32x4){0.f, 0.f, 0.f, 0.f};

  constexpr int ABUF = 128 * 64;             // 8192 elems
  constexpr int BUFSTRIDE = 128 * 64 + 192 * 64;  // 20480 elems

  {
    __hip_bfloat16* As = smem;
    __hip_bfloat16* Bs = smem + ABUF;
#pragma unroll
    for (int i = 0; i < 4; ++i)
      gload_lds16(Abase + (size_t)srowA[i] * NN + scolA[i], As + sc8A[i]);
#pragma unroll
    for (int i = 0; i < 6; ++i)
      gload_lds16(Bbase + (size_t)srowB[i] * NN + scolB[i], Bs + sc8B[i]);
  }

  constexpr int NK = NN / 64;  // 32
  for (int kk = 0; kk < NK; ++kk) {
    const int cur = kk & 1;
    __syncthreads();
    if (kk + 1 < NK) {
      __hip_bfloat16* As = smem + (1 - cur) * BUFSTRIDE;
      __hip_bfloat16* Bs = As + ABUF;
      const int k0 = (kk + 1) * 64;
#pragma unroll
      for (int i = 0; i < 4; ++i)
        gload_lds16(Abase + (size_t)srowA[i] * NN + (k0 + scolA[i]), As + sc8A[i]);
#pragma unroll
      for (int i = 0; i < 6; ++i)
        gload_lds16(Bbase + (size_t)srowB[i] * NN + (k0 + scolB[i]), Bs + sc8B[i]);
    }
    const __hip_bfloat16* As = smem + cur * BUFSTRIDE;
    const __hip_bfloat16* Bs = As + ABUF;
#pragma unroll
    for (int ks = 0; ks < 2; ++ks) {
      bf16x8 af[4], bfr[6];
#pragma unroll
      for (int i = 0; i < 4; ++i) {
        const int rA = wRow * 64 + i * 16 + l16;
        const int pA = (ks * 4 + quad) ^ (rA & 7);
        af[i] = *(const bf16x8*)(As + rA * 64 + pA * 8);
      }
#pragma unroll
      for (int i = 0; i < 6; ++i) {
        const int rB = wCol * 96 + i * 16 + l16;
        const int pB = (ks * 4 + quad) ^ (rB & 7);
        bfr[i] = *(const bf16x8*)(Bs + rB * 64 + pB * 8);
      }
#pragma unroll
      for (int mi = 0; mi < 4; ++mi)
#pragma unroll
        for (int ni = 0; ni < 6; ++ni)
          acc[mi][ni] = __builtin_amdgcn_mfma_f32_16x16x32_bf16(af[mi], bfr[ni], acc[mi][ni], 0, 0, 0);
    }
  }

#pragma unroll
  for (int mi = 0; mi < 4; ++mi) {
#pragma unroll
    for (int r = 0; r < 4; ++r) {
      const int row_g = rowBase + wRow * 64 + mi * 16 + quad * 4 + r;
      const float li = lsum[(size_t)b * NN + row_g];
      const float cw = conf[(size_t)b * NN + row_g];
      const float inv = 1.0f / li;   // li >= 1 (diag contributes exp(0)=1)
      const float* frow = F + ((size_t)b * NN + row_g) * DD;
      float* orow = Out + ((size_t)b * NN + row_g) * DD;
#pragma unroll
      for (int ni = 0; ni < 6; ++ni) {
        const int col_g = colBase + wCol * 96 + ni * 16 + l16;
        const float o = acc[mi][ni][r] * inv;
        orow[col_g] = cw * o + (1.f - cw) * frow[col_g];
      }
    }
  }
}

extern "C" void kernel_launch(void* const* d_in, const int* in_sizes, int n_in,
                              void* d_out, int out_size, void* d_ws, size_t ws_size,
                              hipStream_t stream) {
  const float* F = (const float*)d_in[0];   // final_features
  const float* M = (const float*)d_in[1];   // mid_features
  float* Out = (float*)d_out;

  char* ws = (char*)d_ws;
  // layout: Qn (25165824) | Vt (25165824) | P (67108864) | lsum (65536) | conf (65536)
  __hip_bfloat16* Qn = (__hip_bfloat16*)(ws);
  __hip_bfloat16* Vt = (__hip_bfloat16*)(ws + 25165824);
  __hip_bfloat16* P  = (__hip_bfloat16*)(ws + 50331648);
  float* lsum        = (float*)(ws + 117440512);
  float* conf        = (float*)(ws + 117506048);

  prep_kernel<<<NORM_BLOCKS + TRANS_BLOCKS, 256, 0, stream>>>(M, Qn, lsum, conf, F, Vt);
  gemm_qk_kernel<<<QK_BLOCKS, 256, 0, stream>>>(Qn, P, lsum, (unsigned*)conf);
  gemm_pv_kernel<<<512, 256, 0, stream>>>(P, Vt, lsum, conf, F, Out);
}

// Round 5
// 250.607 us; speedup vs baseline: 1.0634x; 1.0021x over previous
//
#include <hip/hip_runtime.h>
#include <hip/hip_bf16.h>

// Problem constants (setup_inputs: B=8, N=2048, D=768, fp32)
static constexpr int BB = 8;
static constexpr int NN = 2048;
static constexpr int DD = 768;

typedef __attribute__((ext_vector_type(8))) __bf16 bf16x8;
typedef __attribute__((ext_vector_type(4))) float f32x4;

__device__ __forceinline__ void gload_lds16(const __hip_bfloat16* g, __hip_bfloat16* l) {
  __builtin_amdgcn_global_load_lds(
      (const __attribute__((address_space(1))) void*)g,
      (__attribute__((address_space(3))) void*)l,
      16, 0, 0);
}

// ---------------- prep: normalize mid -> Qn bf16 (+zero lsum/conf), transpose F -> Vt bf16 ----------------
static constexpr int NORM_BLOCKS = (BB * NN) / 4;                 // 4096
static constexpr int TRANS_BLOCKS = BB * (NN / 64) * (DD / 64);   // 8*32*12 = 3072
static constexpr int QK_BLOCKS = BB * 136;                        // 1088

__global__ void prep_kernel(const float* __restrict__ mid, __hip_bfloat16* __restrict__ Qn,
                            float* __restrict__ lsum, float* __restrict__ conf,
                            const float* __restrict__ F, __hip_bfloat16* __restrict__ Vt) {
  // bf16 tile, 8.7 KB (row stride 68 keeps ushort4 rows 8B-aligned) -> prep occupancy
  // stays at the 8-block/CU wave cap for BOTH norm and transpose blocks.
  __shared__ __hip_bfloat16 tile[64][68];
  const int t = threadIdx.x;
  if (blockIdx.x < NORM_BLOCKS) {
    const int wave = t >> 6;
    const int lane = t & 63;
    const size_t row = (size_t)blockIdx.x * 4 + wave;
    if (lane == 0) { lsum[row] = 0.f; conf[row] = 0.f; }
    const float* src = mid + row * DD;

    float4 v[3];
    float ss = 0.f;
#pragma unroll
    for (int j = 0; j < 3; ++j) {
      v[j] = *(const float4*)(src + j * 256 + lane * 4);
      ss += v[j].x * v[j].x + v[j].y * v[j].y + v[j].z * v[j].z + v[j].w * v[j].w;
    }
#pragma unroll
    for (int o = 32; o; o >>= 1) ss += __shfl_xor(ss, o, 64);
    const float inv = 1.0f / fmaxf(sqrtf(ss), 1e-12f);

    __hip_bfloat16* dst = Qn + row * DD;
#pragma unroll
    for (int j = 0; j < 3; ++j) {
      union { ushort4 u; __hip_bfloat16 h[4]; } pk;
      pk.h[0] = __float2bfloat16(v[j].x * inv);
      pk.h[1] = __float2bfloat16(v[j].y * inv);
      pk.h[2] = __float2bfloat16(v[j].z * inv);
      pk.h[3] = __float2bfloat16(v[j].w * inv);
      *(ushort4*)(dst + j * 256 + lane * 4) = pk.u;
    }
  } else {
    // ---- vectorized transpose: F[b][n][d] fp32 -> Vt[b][d][n] bf16, 64x64 tiles ----
    const int bid = blockIdx.x - NORM_BLOCKS;
    const int bx = bid % (DD / 64);         // d-tile 0..11
    const int rest = bid / (DD / 64);
    const int by = rest & 31;               // n-tile 0..31
    const int b = rest >> 5;
    const int n0 = by * 64;
    const int d0 = bx * 64;
    const int tr = t >> 4;                  // 0..15
    const int tc = t & 15;                  // 0..15
#pragma unroll
    for (int i = 0; i < 4; ++i) {
      const int n = tr + i * 16;
      const float4 v = *(const float4*)(F + ((size_t)b * NN + n0 + n) * DD + d0 + tc * 4);
      union { ushort4 u; __hip_bfloat16 h[4]; } pk;
      pk.h[0] = __float2bfloat16(v.x);
      pk.h[1] = __float2bfloat16(v.y);
      pk.h[2] = __float2bfloat16(v.z);
      pk.h[3] = __float2bfloat16(v.w);
      *(ushort4*)&tile[n][tc * 4] = pk.u;   // 136B row stride -> 8B aligned
    }
    __syncthreads();
#pragma unroll
    for (int i = 0; i < 4; ++i) {
      const int dd = tr + i * 16;           // local d
      const int n4 = tc * 4;                // local n base
      union { ushort4 u; __hip_bfloat16 h[4]; } pk;
#pragma unroll
      for (int j = 0; j < 4; ++j) pk.h[j] = tile[n4 + j][dd];
      *(ushort4*)(Vt + ((size_t)b * DD + d0 + dd) * NN + n0 + n4) = pk.u;
    }
  }
}

// ---------------- GEMM1 (symmetric): S = Qn·Qnᵀ, upper-triangle tiles only ----------------
// 32 KB LDS (single-buffered staging, no epilogue LDS) -> 3-4 blocks/CU.
__global__ __launch_bounds__(256, 3) void gemm_qk_kernel(
    const __hip_bfloat16* __restrict__ Qn,
    __hip_bfloat16* __restrict__ P,
    float* __restrict__ lsum,
    unsigned* __restrict__ conf) {
  __shared__ __hip_bfloat16 smem[2 * 128 * 64];  // 32 KB: As(16K) + Bs(16K), single-buffered
  const int t = threadIdx.x;

  const int d = blockIdx.x;                // 0..1087 (8 batches x 136 triangle tiles)
  const int b = d & 7;                     // XCD k <- batch k (Qn batch 3 MB fits XCD L2)
  int rem = d >> 3;                        // 0..135
  int ti, tj;
  if (rem < 120) {                         // strict upper triangle (i<j), 120 pairs
    ti = 0;
    while (rem >= 15 - ti) { rem -= 15 - ti; ++ti; }
    tj = ti + 1 + rem;
  } else {                                 // 16 diagonal tiles, scheduled last
    ti = tj = rem - 120;
  }
  const int rowBase = ti * 128;
  const int colBase = tj * 128;
  const bool offdiag = (ti != tj);

  const int lane = t & 63;
  const int wave = t >> 6;
  const int wRow = wave >> 1;
  const int wCol = wave & 1;
  const int quad = lane >> 4;
  const int l16 = lane & 15;

  const __hip_bfloat16* Abase = Qn + ((size_t)b * NN + rowBase) * DD;
  const __hip_bfloat16* Bbase = Qn + ((size_t)b * NN + colBase) * DD;

  // staging slots (lane-contiguous dest for global_load_lds; source XOR-swizzled)
  int srow[4], scol[4], sc8[4];
#pragma unroll
  for (int i = 0; i < 4; ++i) {
    const int c = i * 256 + t;
    srow[i] = c >> 3;
    const int col8 = (c & 7) ^ ((c >> 3) & 7);
    scol[i] = col8 * 8;
    sc8[i] = c * 8;
  }

  f32x4 acc[4][4];
#pragma unroll
  for (int i = 0; i < 4; ++i)
#pragma unroll
    for (int j = 0; j < 4; ++j) acc[i][j] = (f32x4){0.f, 0.f, 0.f, 0.f};

  __hip_bfloat16* As = smem;
  __hip_bfloat16* Bs = smem + 128 * 64;

  // prologue: stage tile 0
#pragma unroll
  for (int i = 0; i < 4; ++i) {
    gload_lds16(Abase + (size_t)srow[i] * DD + scol[i], As + sc8[i]);
    gload_lds16(Bbase + (size_t)srow[i] * DD + scol[i], Bs + sc8[i]);
  }

  constexpr int NK = DD / 64;  // 12
  for (int kk = 0; kk < NK; ++kk) {
    __syncthreads();  // staged data visible (compiler drains vmcnt before barrier)
#pragma unroll
    for (int ks = 0; ks < 2; ++ks) {
      bf16x8 af[4], bfr[4];
#pragma unroll
      for (int i = 0; i < 4; ++i) {
        const int rA = wRow * 64 + i * 16 + l16;
        const int rB = wCol * 64 + i * 16 + l16;
        const int pA = (ks * 4 + quad) ^ (rA & 7);
        const int pB = (ks * 4 + quad) ^ (rB & 7);
        af[i]  = *(const bf16x8*)(As + rA * 64 + pA * 8);
        bfr[i] = *(const bf16x8*)(Bs + rB * 64 + pB * 8);
      }
#pragma unroll
      for (int mi = 0; mi < 4; ++mi)
#pragma unroll
        for (int ni = 0; ni < 4; ++ni)
          acc[mi][ni] = __builtin_amdgcn_mfma_f32_16x16x32_bf16(af[mi], bfr[ni], acc[mi][ni], 0, 0, 0);
    }
    if (kk + 1 < NK) {
      __syncthreads();  // all waves done reading buf
      const int k0 = (kk + 1) * 64;
#pragma unroll
      for (int i = 0; i < 4; ++i) {
        gload_lds16(Abase + (size_t)srow[i] * DD + (k0 + scol[i]), As + sc8[i]);
        gload_lds16(Bbase + (size_t)srow[i] * DD + (k0 + scol[i]), Bs + sc8[i]);
      }
    }
  }

  // ---- epilogue: stats + direct-from-register P stores (no LDS, no barriers) ----
  __hip_bfloat16* Pdir = P + ((size_t)b * NN + rowBase) * NN + colBase;  // [row][col]
  __hip_bfloat16* Pmir = P + ((size_t)b * NN + colBase) * NN + rowBase;  // [col][row]

  float csum[4] = {0.f, 0.f, 0.f, 0.f};
  float cmax[4] = {0.f, 0.f, 0.f, 0.f};  // clamp at 0 valid (diag of full matrix is 0)

#pragma unroll
  for (int mi = 0; mi < 4; ++mi) {
    const int rbase = wRow * 64 + mi * 16 + quad * 4;
    float rs[4] = {0.f, 0.f, 0.f, 0.f};
    float rm[4] = {0.f, 0.f, 0.f, 0.f};
#pragma unroll
    for (int ni = 0; ni < 4; ++ni) {
      const int colL = wCol * 64 + ni * 16 + l16;
      const int col_g = colBase + colL;
      union { ushort4 u; __hip_bfloat16 h[4]; } pk;
#pragma unroll
      for (int r = 0; r < 4; ++r) {
        const int rowL = rbase + r;
        float s = acc[mi][ni][r];
        if (rowBase + rowL == col_g) s = 0.f;   // only possible on diagonal tiles
        const float p = __expf(s);              // T=1; |s|<=1 so no max-subtraction needed
        rm[r] = fmaxf(rm[r], s);
        rs[r] += p;
        csum[ni] += p;
        cmax[ni] = fmaxf(cmax[ni], s);
        pk.h[r] = __float2bfloat16(p);
        Pdir[(size_t)rowL * NN + colL] = pk.h[r];           // scalar 2B store
      }
      if (offdiag) {  // mirror: 4 consecutive cols per lane -> 8B store (rbase%4==0)
        *(ushort4*)(Pmir + (size_t)colL * NN + rbase) = pk.u;
      }
    }
#pragma unroll
    for (int r = 0; r < 4; ++r) {
      float ps = rs[r], mx = rm[r];
#pragma unroll
      for (int o = 1; o < 16; o <<= 1) {
        ps += __shfl_xor(ps, o, 64);
        mx = fmaxf(mx, __shfl_xor(mx, o, 64));
      }
      if (l16 == 0) {
        const int row_g = rowBase + rbase + r;
        atomicAdd(lsum + (size_t)b * NN + row_g, ps);
        atomicMax(conf + (size_t)b * NN + row_g, __float_as_uint(mx));  // nonneg: uint order == float order
      }
    }
  }

  // column stats -> stripe tj rows (mirror contribution), off-diag only
  if (offdiag) {
#pragma unroll
    for (int ni = 0; ni < 4; ++ni) {
      float cs = csum[ni];
      float cm = cmax[ni];
      cs += __shfl_xor(cs, 16, 64); cm = fmaxf(cm, __shfl_xor(cm, 16, 64));
      cs += __shfl_xor(cs, 32, 64); cm = fmaxf(cm, __shfl_xor(cm, 32, 64));
      if (quad == 0) {
        const int col_g = colBase + wCol * 64 + ni * 16 + l16;
        atomicAdd(lsum + (size_t)b * NN + col_g, cs);
        atomicMax(conf + (size_t)b * NN + col_g, __float_as_uint(cm));
      }
    }
  }
}

// ---------------- GEMM2: O = P·V ; 256x192 tile, 512 thr, counted-vmcnt 4-phase pipeline ----------------
// T3+T4+T5 port: raw s_barrier (no vmcnt(0) drain), loads issued across phases into the
// other dbuf half, waits counted (vmcnt(2)/vmcnt(5)), setprio around each MFMA cluster.
// Per-wave (4M x 2N grid): rows {wRow*32+0..31} u {128+wRow*32+..}, cols {wCol*48+0..47} u {96+wCol*48+..}.
// Per-wave per-tile issue order (constant, vmcnt arithmetic depends on it): A01, B012, A23.
__global__ __launch_bounds__(512, 2) void gemm_pv_kernel(
    const __hip_bfloat16* __restrict__ P,    // [B][N][N]
    const __hip_bfloat16* __restrict__ Vt,   // [B][D][N]
    const float* __restrict__ lsum,
    const float* __restrict__ conf,
    const float* __restrict__ F,             // [B][N][D] fp32
    float* __restrict__ Out) {
  constexpr int ASZ = 256 * 64;              // 16384 elems (32 KB)
  constexpr int BSZ = 192 * 64;              // 12288 elems (24 KB)
  constexpr int BUF = ASZ + BSZ;             // 28672 elems (56 KB)
  __shared__ __hip_bfloat16 smem[2 * BUF];   // 112 KB -> 1 block/CU, 8 waves

  const int x = blockIdx.x;                  // 0..255 = 8 batches x (8 rowTiles x 4 colTiles)
  const int b = x & 7;                       // XCD k <- batch k
  const int work = x >> 3;                   // 0..31
  const int rowBase = (work >> 2) * 256;
  const int colBase = (work & 3) * 192;

  const int t = threadIdx.x;                 // 0..511
  const int lane = t & 63;
  const int wave = t >> 6;                   // 0..7
  const int wRow = wave >> 1;                // 0..3
  const int wCol = wave & 1;                 // 0..1
  const int quad = lane >> 4;
  const int l16 = lane & 15;

  const __hip_bfloat16* Abase = P + (size_t)b * NN * NN + (size_t)rowBase * NN;
  const __hip_bfloat16* Bbase = Vt + (size_t)b * DD * NN + (size_t)colBase * NN;

  // staging: A = 2048 16B-chunks (4 loads/thread), B = 1536 chunks (3 loads/thread)
  int offA[4], dstA[4];
#pragma unroll
  for (int i = 0; i < 4; ++i) {
    const int c = i * 512 + t;
    offA[i] = (c >> 3) * NN + (((c & 7) ^ ((c >> 3) & 7)) << 3);
    dstA[i] = c * 8;
  }
  int offB[3], dstB[3];
#pragma unroll
  for (int i = 0; i < 3; ++i) {
    const int c = i * 512 + t;
    offB[i] = (c >> 3) * NN + (((c & 7) ^ ((c >> 3) & 7)) << 3);
    dstB[i] = c * 8;
  }

  f32x4 acc[4][6];
#pragma unroll
  for (int i = 0; i < 4; ++i)
#pragma unroll
    for (int j = 0; j < 6; ++j) acc[i][j] = (f32x4){0.f, 0.f, 0.f, 0.f};

  // row/col of each fragment (local to tile)
  int rowL[4], colL[6];
#pragma unroll
  for (int i = 0; i < 4; ++i) rowL[i] = (i < 2) ? (wRow * 32 + i * 16) : (128 + wRow * 32 + (i - 2) * 16);
#pragma unroll
  for (int j = 0; j < 6; ++j) colL[j] = (j < 3) ? (wCol * 48 + j * 16) : (96 + wCol * 48 + (j - 3) * 16);

  // prologue: tile 0 into buf0 in steady-state issue order A01, B012, A23
  {
    __hip_bfloat16* As = smem;
    __hip_bfloat16* Bs = smem + ASZ;
    gload_lds16(Abase + offA[0], As + dstA[0]);
    gload_lds16(Abase + offA[1], As + dstA[1]);
    gload_lds16(Bbase + offB[0], Bs + dstB[0]);
    gload_lds16(Bbase + offB[1], Bs + dstB[1]);
    gload_lds16(Bbase + offB[2], Bs + dstB[2]);
    gload_lds16(Abase + offA[2], As + dstA[2]);
    gload_lds16(Abase + offA[3], As + dstA[3]);
  }

  constexpr int NK = NN / 64;  // 32
  for (int kk = 0; kk < NK; ++kk) {
    const int cur = kk & 1;
    const __hip_bfloat16* As = smem + cur * BUF;
    const __hip_bfloat16* Bs = As + ASZ;
    __hip_bfloat16* An = smem + (1 - cur) * BUF;
    __hip_bfloat16* Bn = An + ASZ;
    const int k0 = (kk + 1) * 64;
    const bool more = (kk + 1 < NK);

    bf16x8 af[4][2], bfr[6][2];

    // ---- phase 0: wait A01(k)+B012(k); issue A01(k+1); MFMA af01 x bf012 ----
    asm volatile("s_waitcnt vmcnt(2)" ::: "memory");  // keep newest 2 (A23(k)) in flight
    __builtin_amdgcn_s_barrier();
    asm volatile("" ::: "memory");
    if (more) {
      gload_lds16(Abase + offA[0] + k0, An + dstA[0]);
      gload_lds16(Abase + offA[1] + k0, An + dstA[1]);
    }
#pragma unroll
    for (int i = 0; i < 2; ++i)
#pragma unroll
      for (int ks = 0; ks < 2; ++ks) {
        const int r = rowL[i] + l16;
        af[i][ks] = *(const bf16x8*)(As + r * 64 + (((ks * 4 + quad) ^ (r & 7)) << 3));
      }
#pragma unroll
    for (int j = 0; j < 3; ++j)
#pragma unroll
      for (int ks = 0; ks < 2; ++ks) {
        const int r = colL[j] + l16;
        bfr[j][ks] = *(const bf16x8*)(Bs + r * 64 + (((ks * 4 + quad) ^ (r & 7)) << 3));
      }
    __builtin_amdgcn_s_setprio(1);
#pragma unroll
    for (int i = 0; i < 2; ++i)
#pragma unroll
      for (int j = 0; j < 3; ++j)
#pragma unroll
        for (int ks = 0; ks < 2; ++ks)
          acc[i][j] = __builtin_amdgcn_mfma_f32_16x16x32_bf16(af[i][ks], bfr[j][ks], acc[i][j], 0, 0, 0);
    __builtin_amdgcn_s_setprio(0);

    // ---- phase 1: issue B012(k+1); MFMA af01 x bf345 ----
    __builtin_amdgcn_s_barrier();
    asm volatile("" ::: "memory");
    if (more) {
      gload_lds16(Bbase + offB[0] + k0, Bn + dstB[0]);
      gload_lds16(Bbase + offB[1] + k0, Bn + dstB[1]);
      gload_lds16(Bbase + offB[2] + k0, Bn + dstB[2]);
    }
#pragma unroll
    for (int j = 3; j < 6; ++j)
#pragma unroll
      for (int ks = 0; ks < 2; ++ks) {
        const int r = colL[j] + l16;
        bfr[j][ks] = *(const bf16x8*)(Bs + r * 64 + (((ks * 4 + quad) ^ (r & 7)) << 3));
      }
    __builtin_amdgcn_s_setprio(1);
#pragma unroll
    for (int i = 0; i < 2; ++i)
#pragma unroll
      for (int j = 3; j < 6; ++j)
#pragma unroll
        for (int ks = 0; ks < 2; ++ks)
          acc[i][j] = __builtin_amdgcn_mfma_f32_16x16x32_bf16(af[i][ks], bfr[j][ks], acc[i][j], 0, 0, 0);
    __builtin_amdgcn_s_setprio(0);

    // ---- phase 2: wait A23(k); issue A23(k+1); MFMA af23 x bf012 ----
    if (more) asm volatile("s_waitcnt vmcnt(5)" ::: "memory");  // keep A01(k+1)+B012(k+1) in flight
    else      asm volatile("s_waitcnt vmcnt(0)" ::: "memory");  // peeled tail: nothing newer
    __builtin_amdgcn_s_barrier();
    asm volatile("" ::: "memory");
    if (more) {
      gload_lds16(Abase + offA[2] + k0, An + dstA[2]);
      gload_lds16(Abase + offA[3] + k0, An + dstA[3]);
    }
#pragma unroll
    for (int i = 2; i < 4; ++i)
#pragma unroll
      for (int ks = 0; ks < 2; ++ks) {
        const int r = rowL[i] + l16;
        af[i][ks] = *(const bf16x8*)(As + r * 64 + (((ks * 4 + quad) ^ (r & 7)) << 3));
      }
    __builtin_amdgcn_s_setprio(1);
#pragma unroll
    for (int i = 2; i < 4; ++i)
#pragma unroll
      for (int j = 0; j < 3; ++j)
#pragma unroll
        for (int ks = 0; ks < 2; ++ks)
          acc[i][j] = __builtin_amdgcn_mfma_f32_16x16x32_bf16(af[i][ks], bfr[j][ks], acc[i][j], 0, 0, 0);
    __builtin_amdgcn_s_setprio(0);

    // ---- phase 3: MFMA af23 x bf345 ----
    __builtin_amdgcn_s_barrier();
    asm volatile("" ::: "memory");
    __builtin_amdgcn_s_setprio(1);
#pragma unroll
    for (int i = 2; i < 4; ++i)
#pragma unroll
      for (int j = 3; j < 6; ++j)
#pragma unroll
        for (int ks = 0; ks < 2; ++ks)
          acc[i][j] = __builtin_amdgcn_mfma_f32_16x16x32_bf16(af[i][ks], bfr[j][ks], acc[i][j], 0, 0, 0);
    __builtin_amdgcn_s_setprio(0);
  }

  // ---- epilogue: normalize + blend, direct f32 stores (16 lanes = 64B runs) ----
#pragma unroll
  for (int i = 0; i < 4; ++i) {
#pragma unroll
    for (int r = 0; r < 4; ++r) {
      const int row_g = rowBase + rowL[i] + quad * 4 + r;
      const float li = lsum[(size_t)b * NN + row_g];
      const float cw = conf[(size_t)b * NN + row_g];
      const float inv = 1.0f / li;   // li >= 1 (diag contributes exp(0)=1)
      const float* frow = F + ((size_t)b * NN + row_g) * DD;
      float* orow = Out + ((size_t)b * NN + row_g) * DD;
#pragma unroll
      for (int j = 0; j < 6; ++j) {
        const int col_g = colBase + colL[j] + l16;
        const float o = acc[i][j][r] * inv;
        orow[col_g] = cw * o + (1.f - cw) * frow[col_g];
      }
    }
  }
}

extern "C" void kernel_launch(void* const* d_in, const int* in_sizes, int n_in,
                              void* d_out, int out_size, void* d_ws, size_t ws_size,
                              hipStream_t stream) {
  const float* F = (const float*)d_in[0];   // final_features
  const float* M = (const float*)d_in[1];   // mid_features
  float* Out = (float*)d_out;

  char* ws = (char*)d_ws;
  // layout: Qn (25165824) | Vt (25165824) | P (67108864) | lsum (65536) | conf (65536)
  __hip_bfloat16* Qn = (__hip_bfloat16*)(ws);
  __hip_bfloat16* Vt = (__hip_bfloat16*)(ws + 25165824);
  __hip_bfloat16* P  = (__hip_bfloat16*)(ws + 50331648);
  float* lsum        = (float*)(ws + 117440512);
  float* conf        = (float*)(ws + 117506048);

  prep_kernel<<<NORM_BLOCKS + TRANS_BLOCKS, 256, 0, stream>>>(M, Qn, lsum, conf, F, Vt);
  gemm_qk_kernel<<<QK_BLOCKS, 256, 0, stream>>>(Qn, P, lsum, (unsigned*)conf);
  gemm_pv_kernel<<<256, 512, 0, stream>>>(P, Vt, lsum, conf, F, Out);
}